// Round 9
// baseline (342.153 us; speedup 1.0000x reference)
//
#include <hip/hip_runtime.h>
#include <hip/hip_bf16.h>
#include <cstdint>
#include <cstddef>

// ---------- types ----------
typedef __attribute__((ext_vector_type(8))) _Float16 half8;
typedef __attribute__((ext_vector_type(4))) float floatx4;

#define MFMA16(a, b, c) __builtin_amdgcn_mfma_f32_16x16x32_f16((a), (b), (c), 0, 0, 0)

// direct global->LDS DMA, 16B per lane, dest = uniform base + lane*16
#define GLOAD_LDS16(g, l)                                                     \
    __builtin_amdgcn_global_load_lds(                                         \
        (const __attribute__((address_space(1))) void*)(g),                   \
        (__attribute__((address_space(3))) void*)(l), 16, 0, 0)

// Barrier that waits LDS ops only — does NOT drain vmcnt, so register
// prefetch loads issued before it stay in flight across the barrier.
#define BARLG() asm volatile("s_waitcnt lgkmcnt(0)\ns_barrier" ::: "memory")

// Problem constants: A=64, T=512, D=256, H=4, HD=64
#define NFEAT 8388608   // 64*512*256

// ---------- staging helpers ----------
// fp32 source, cvt in-register: 128 rows x 64 cols -> LDS rows of dst_stride,
// XOR swizzle within the 8-chunk slab
__device__ __forceinline__ void stage_f32_s(
    const float* __restrict__ src, _Float16* __restrict__ lds, int tid,
    int dst_stride)
{
#pragma unroll
    for (int i = 0; i < 4; ++i) {
        int g   = tid + 256 * i;           // 1024 groups of 8 halfs
        int row = g >> 3, chd = g & 7;
        int chs = chd ^ (row & 7);
        const float* s = src + (size_t)row * 256 + chs * 8;
        float4 v0 = *(const float4*)s;
        float4 v1 = *(const float4*)(s + 4);
        half8 h = { (_Float16)v0.x, (_Float16)v0.y, (_Float16)v0.z, (_Float16)v0.w,
                    (_Float16)v1.x, (_Float16)v1.y, (_Float16)v1.z, (_Float16)v1.w };
        *(half8*)(&lds[row * dst_stride + chd * 8]) = h;
    }
}

// ---------- fused QKV GEMM (R6 structure + LDS-staged coalesced epilogue) ----------
// 1D grid 512 blocks: xcd = n&7; per XCD: 32 bm x 2 bn. X tile [128x256]
// staged ONCE (fp32->fp16 inline). Then 3 weight GEMMs; each 64-wide K-step's
// W tile is prefetched into REGISTERS during the previous step's MFMA phase
// and cvt+written to LDS after the barrier (BARLG keeps prefetch in flight).
// EPILOGUE: C tile staged through Ws in 2 rounds of [64x128] fp16 (XOR
// swizzle), then copied out with coalesced half8 stores (256B row segments)
// instead of 192 scalar 2B stores. LDS 80 KB -> 2 blk/CU.
__global__ __launch_bounds__(256) void qkv_fused(
    const float* __restrict__ feat,
    const float* __restrict__ Wq, const float* __restrict__ Wk,
    const float* __restrict__ Wv,
    const float* __restrict__ bq, const float* __restrict__ bk,
    const float* __restrict__ bv,
    _Float16* __restrict__ Qb, _Float16* __restrict__ Kb, _Float16* __restrict__ Vb)
{
    __shared__ _Float16 Xs[128 * 256];   // 64 KB, XOR-swizzled per 64-col slab
    __shared__ _Float16 Ws[128 * 64];    // 16 KB (W K-tile; reused as C stage)

    const int n   = blockIdx.x;
    const int idx = n >> 3;
    const int bm  = (n & 7) * 32 + (idx >> 1);
    const int bn  = idx & 1;

    const int tid  = threadIdx.x;
    const int lane = tid & 63, wid = tid >> 6;
    const int quad = lane >> 4, l16 = lane & 15;
    const int wm = wid & 1, wn = wid >> 1;

    // stage X tile once: 4 slabs of 64 cols
    const float* Xg = feat + (size_t)bm * 128 * 256;
#pragma unroll
    for (int slab = 0; slab < 4; ++slab)
        stage_f32_s(Xg + slab * 64, Xs + slab * 64, tid, 256);

    // W K-tile prefetch registers: 128 rows x 64 cols fp32 = 8 float4/thread
    float4 wv0[4], wv1[4];
    auto loadw = [&](const float* __restrict__ src) {
#pragma unroll
        for (int i = 0; i < 4; ++i) {
            int g = tid + 256 * i, row = g >> 3, chd = g & 7;
            int chs = chd ^ (row & 7);
            const float* s = src + (size_t)row * 256 + chs * 8;
            wv0[i] = *(const float4*)s;
            wv1[i] = *(const float4*)(s + 4);
        }
    };
    auto writew = [&]() {
#pragma unroll
        for (int i = 0; i < 4; ++i) {
            int g = tid + 256 * i, row = g >> 3, chd = g & 7;
            half8 h = { (_Float16)wv0[i].x, (_Float16)wv0[i].y,
                        (_Float16)wv0[i].z, (_Float16)wv0[i].w,
                        (_Float16)wv1[i].x, (_Float16)wv1[i].y,
                        (_Float16)wv1[i].z, (_Float16)wv1[i].w };
            *(half8*)(&Ws[row * 64 + chd * 8]) = h;
        }
    };

    const size_t boff = (size_t)bn * 128 * 256;
    loadw(Wq + boff);      // prefetch (z=0, ks=0)
    __syncthreads();       // X tile ready (single full drain per block)

#pragma unroll 1
    for (int z = 0; z < 3; ++z) {
        const float* Wz   = (z == 0) ? Wq : (z == 1) ? Wk : Wv;
        const float* Wnz  = (z == 0) ? Wk : Wv;   // next z's W (unused at z==2)
        const float* bias = (z == 0) ? bq : (z == 1) ? bk : bv;
        _Float16*    outp = (z == 0) ? Qb : (z == 1) ? Kb : Vb;

        floatx4 acc[4][4] = {};
#pragma unroll
        for (int ks = 0; ks < 4; ++ks) {   // k0 = ks*64
            BARLG();                       // prev step's Ws reads complete
            writew();                      // cvt + LDS-write current K-tile
            if (ks < 3)      loadw(Wz + boff + (ks + 1) * 64);   // prefetch next
            else if (z < 2)  loadw(Wnz + boff);
            BARLG();                       // Ws ready; prefetch stays in flight
#pragma unroll
            for (int kh = 0; kh < 2; ++kh) {
                half8 af[4], bf[4];
#pragma unroll
                for (int mi = 0; mi < 4; ++mi) {
                    int row = wm * 64 + mi * 16 + l16;
                    int cs  = (kh * 4 + quad) ^ (row & 7);
                    af[mi] = *(const half8*)(&Xs[row * 256 + ks * 64 + cs * 8]);
                }
#pragma unroll
                for (int ni = 0; ni < 4; ++ni) {
                    int row = wn * 64 + ni * 16 + l16;
                    int cs  = (kh * 4 + quad) ^ (row & 7);
                    bf[ni] = *(const half8*)(&Ws[row * 64 + cs * 8]);
                }
#pragma unroll
                for (int mi = 0; mi < 4; ++mi)
#pragma unroll
                    for (int ni = 0; ni < 4; ++ni)
                        acc[mi][ni] = MFMA16(af[mi], bf[ni], acc[mi][ni]);
            }
        }

        // ---- epilogue z: 2 rounds of [64 rows x 128 cols] fp16 through Ws,
        //      then coalesced half8 copy-out ----
#pragma unroll 1
        for (int rp = 0; rp < 2; ++rp) {
            BARLG();   // prior Ws readers (MFMA / prev round copy) done
#pragma unroll
            for (int m2 = 0; m2 < 2; ++m2) {
                int mi = rp * 2 + m2;
#pragma unroll
                for (int ni = 0; ni < 4; ++ni) {
                    int lcol = wn * 64 + ni * 16 + l16;
                    float bv2 = bias[bn * 128 + lcol];
#pragma unroll
                    for (int r = 0; r < 4; ++r) {
                        int lrow = m2 * 32 + wm * 16 + quad * 4 + r;
                        int sc   = (lcol >> 3) ^ (lrow & 7);
                        Ws[lrow * 128 + sc * 8 + (lcol & 7)] =
                            (_Float16)(acc[mi][ni][r] + bv2);
                    }
                }
            }
            BARLG();   // staged tile visible
#pragma unroll
            for (int i = 0; i < 4; ++i) {
                int g    = tid + 256 * i;        // 1024 half8-groups
                int lrow = g >> 4, lc = g & 15;
                int sc   = lc ^ (lrow & 7);
                half8 hv = *(const half8*)(&Ws[lrow * 128 + sc * 8]);
                int m2   = lrow >> 5, wmp = (lrow >> 4) & 1, qr = lrow & 15;
                int grow = bm * 128 + wmp * 64 + (rp * 2 + m2) * 16 + qr;
                *(half8*)(&outp[(size_t)grow * 256 + bn * 128 + lc * 8]) = hv;
            }
        }
    }
}

// ---------- out GEMM: C[128x128] = attnH[128x256] * Wo^T + bias ----------
// Whole A tile [128x256] staged once via DMA (one drain); Wo K-tiles
// register-prefetched. EPILOGUE: C staged through Bs in 4 rounds of
// [32x128] fp32 (XOR swizzle), coalesced float4 copy-out. LDS 80 KB.
__global__ __launch_bounds__(256) void out_gemm(
    const _Float16* __restrict__ attnH, const float* __restrict__ Wo,
    const float* __restrict__ bo, float* __restrict__ out)
{
    __shared__ _Float16 As[128 * 256];   // 64 KB: 4 packed slabs [128][64]
    __shared__ _Float16 Bs[128 * 64];    // 16 KB (W K-tile; reused as C stage)

    const int n   = blockIdx.x;
    const int idx = n >> 3;
    const int bm  = (n & 7) * 32 + (idx >> 1);
    const int bn  = idx & 1;

    const int tid  = threadIdx.x;
    const int lane = tid & 63, wid = tid >> 6;
    const int quad = lane >> 4, l16 = lane & 15;
    const int wm = wid & 1, wn = wid >> 1;

    // ---- stage whole A tile via DMA: 4 slabs x 4 groups/wave ----
#pragma unroll
    for (int slab = 0; slab < 4; ++slab)
#pragma unroll
        for (int i = 0; i < 4; ++i) {
            int grp = wid * 4 + i;             // 16 groups of 8 rows
            int row = grp * 8 + (lane >> 3);
            int sc  = (lane & 7) ^ (row & 7);
            GLOAD_LDS16(attnH + (size_t)(bm * 128 + row) * 256 + slab * 64 + sc * 8,
                        As + slab * 8192 + grp * 512);
        }

    float4 wv0[4], wv1[4];
    auto loadw = [&](const float* __restrict__ src) {
#pragma unroll
        for (int i = 0; i < 4; ++i) {
            int g = tid + 256 * i, row = g >> 3, chd = g & 7;
            int chs = chd ^ (row & 7);
            const float* s = src + (size_t)row * 256 + chs * 8;
            wv0[i] = *(const float4*)s;
            wv1[i] = *(const float4*)(s + 4);
        }
    };
    auto writew = [&]() {
#pragma unroll
        for (int i = 0; i < 4; ++i) {
            int g = tid + 256 * i, row = g >> 3, chd = g & 7;
            half8 h = { (_Float16)wv0[i].x, (_Float16)wv0[i].y,
                        (_Float16)wv0[i].z, (_Float16)wv0[i].w,
                        (_Float16)wv1[i].x, (_Float16)wv1[i].y,
                        (_Float16)wv1[i].z, (_Float16)wv1[i].w };
            *(half8*)(&Bs[row * 64 + chd * 8]) = h;
        }
    };

    const size_t boff = (size_t)bn * 128 * 256;
    loadw(Wo + boff);      // prefetch ks=0
    __syncthreads();       // A tile ready (single full drain)

    floatx4 acc[4][4] = {};
#pragma unroll
    for (int ks = 0; ks < 4; ++ks) {
        BARLG();
        writew();
        if (ks < 3) loadw(Wo + boff + (ks + 1) * 64);
        BARLG();
#pragma unroll
        for (int kh = 0; kh < 2; ++kh) {
            half8 af[4], bf[4];
#pragma unroll
            for (int mi = 0; mi < 4; ++mi) {
                int row = wm * 64 + mi * 16 + l16;
                int cs  = (kh * 4 + quad) ^ (row & 7);
                af[mi] = *(const half8*)(&As[ks * 8192 + row * 64 + cs * 8]);
            }
#pragma unroll
            for (int ni = 0; ni < 4; ++ni) {
                int row = wn * 64 + ni * 16 + l16;
                int cs  = (kh * 4 + quad) ^ (row & 7);
                bf[ni] = *(const half8*)(&Bs[row * 64 + cs * 8]);
            }
#pragma unroll
            for (int mi = 0; mi < 4; ++mi)
#pragma unroll
                for (int ni = 0; ni < 4; ++ni)
                    acc[mi][ni] = MFMA16(af[mi], bf[ni], acc[mi][ni]);
        }
    }

    // ---- epilogue: 4 rounds of [32 rows x 128 cols] fp32 through Bs ----
    float* Bf = (float*)Bs;
#pragma unroll 1
    for (int mi = 0; mi < 4; ++mi) {
        BARLG();   // prior Bs readers done
#pragma unroll
        for (int ni = 0; ni < 4; ++ni) {
            int lcol = wn * 64 + ni * 16 + l16;
            float bv = bo[bn * 128 + lcol];
#pragma unroll
            for (int r = 0; r < 4; ++r) {
                int lrow = wm * 16 + quad * 4 + r;
                int sc   = (lcol >> 2) ^ ((lrow & 7) << 2);
                Bf[lrow * 128 + sc * 4 + (lcol & 3)] = acc[mi][ni][r] + bv;
            }
        }
        BARLG();
#pragma unroll
        for (int i = 0; i < 4; ++i) {
            int g    = tid + 256 * i;          // 1024 float4-groups
            int lrow = g >> 5, lc = g & 31;
            int sc   = lc ^ ((lrow & 7) << 2);
            float4 v = *(const float4*)(&Bf[lrow * 128 + sc * 4]);
            int wmp  = lrow >> 4, qr = lrow & 15;
            int grow = bm * 128 + wmp * 64 + mi * 16 + qr;
            *(float4*)(&out[(size_t)grow * 256 + bn * 128 + lc * 4]) = v;
        }
    }
}

// ---------- banded sparse attention (R0 form + wave-local staged O store) ----------
// 1D grid 2048: xcd = n&7; per XCD 8 animals x (8 qt x 4 h), h fastest then qt
// (adjacent qtiles share K/V band rows -> same-XCD L2 locality).
__global__ __launch_bounds__(256) void attn_kernel(
    const _Float16* __restrict__ Qb, const _Float16* __restrict__ Kb,
    const _Float16* __restrict__ Vb, const float* __restrict__ positions,
    const int* __restrict__ mdp, const int* __restrict__ twp,
    _Float16* __restrict__ attnb)
{
    const int n   = blockIdx.x;
    const int idx = n >> 3;
    const int a   = (n & 7) * 8 + (idx >> 5);
    const int rem = idx & 31;
    const int qt  = rem >> 2, h = rem & 3;

    const int q0 = qt * 64;
    const int s_base = q0 - 64;
    const int tid = threadIdx.x, lane = tid & 63, wid = tid >> 6;
    const int quad = lane >> 4, l16 = lane & 15;

    // LDS 48 KB -> 3 blocks/CU
    __shared__ _Float16 KPs[192 * 64];   // packed K (XOR), reused as packed P
    __shared__ _Float16 Vt[64 * 192];    // packed V^T (XOR chunk swizzle)

    const size_t abase = (size_t)a * 512;
    const int md = *mdp, tw = *twp;
    const float md2 = (float)(md * md);

    // ---- hoisted per-wave Q fragment + q-position loads ----
    const size_t qrow = abase + q0 + wid * 16 + l16;
    half8 aq0 = *(const half8*)(Qb + qrow * 256 + h * 64 + quad * 8);
    half8 aq1 = *(const half8*)(Qb + qrow * 256 + h * 64 + 32 + quad * 8);
    float qpx[4], qpy[4];
    int trow[4];
#pragma unroll
    for (int r = 0; r < 4; ++r) {
        int m = wid * 16 + quad * 4 + r;
        trow[r] = q0 + m;
        float2 qp = *(const float2*)(positions + (abase + q0 + m) * 2);
        qpx[r] = qp.x;
        qpy[r] = qp.y;
    }

    // ---- stage K band via DMA: packed [192][64], source-side XOR swizzle ----
#pragma unroll
    for (int i = 0; i < 6; ++i) {
        int grp = wid * 6 + i;             // 24 groups of 8 rows
        int si  = grp * 8 + (lane >> 3);
        int sc  = min(max(s_base + si, 0), 511);
        int ch  = (lane & 7) ^ (si & 7);
        GLOAD_LDS16(Kb + (abase + sc) * 256 + h * 64 + ch * 8, KPs + grp * 512);
    }
    // ---- stage V^T packed [64][192], XOR chunk swizzle, paired b32 writes ----
#pragma unroll
    for (int i = 0; i < 3; ++i) {
        int g   = tid + 256 * i;           // 768 pair-groups
        int si2 = (g % 96) * 2;
        int d0  = (g / 96) * 8;
        int sa  = min(max(s_base + si2, 0), 511);
        int sb  = min(max(s_base + si2 + 1, 0), 511);
        half8 v0 = *(const half8*)(Vb + (abase + sa) * 256 + h * 64 + d0);
        half8 v1 = *(const half8*)(Vb + (abase + sb) * 256 + h * 64 + d0);
        int c = si2 >> 3;                  // chunk within 24
#pragma unroll
        for (int j = 0; j < 8; ++j) {
            int d  = d0 + j;
            int cs = (c & ~7) | ((c & 7) ^ (d & 7));
            union { _Float16 hh[2]; uint32_t u; } p;
            p.hh[0] = v0[j]; p.hh[1] = v1[j];
            *(uint32_t*)(&Vt[d * 192 + cs * 8 + (si2 & 7)]) = p.u;
        }
    }
    __syncthreads();

    // ---- S = Q K^T over 12 key tiles ----
    floatx4 S[12];
#pragma unroll
    for (int j = 0; j < 12; ++j) {
        int si = j * 16 + l16;
        half8 bk0 = *(const half8*)(&KPs[si * 64 + ((quad) ^ (si & 7)) * 8]);
        half8 bk1 = *(const half8*)(&KPs[si * 64 + ((4 + quad) ^ (si & 7)) * 8]);
        floatx4 acc = {};
        acc = MFMA16(aq0, bk0, acc);
        acc = MFMA16(aq1, bk1, acc);
        int sr = s_base + si;
        int sc = min(max(sr, 0), 511);
        float2 kp = *(const float2*)(positions + (abase + sc) * 2);
        bool svalid = (sr >= 0) && (sr < 512);
#pragma unroll
        for (int r = 0; r < 4; ++r) {
            float dx = qpx[r] - kp.x, dy = qpy[r] - kp.y;
            float d2 = dx * dx + dy * dy;
            int dt = trow[r] - sr; dt = dt < 0 ? -dt : dt;
            bool ok = svalid && (d2 <= md2) && (dt <= tw);
            S[j][r] = ok ? acc[r] * 0.125f : -1e30f;   // scale = 1/sqrt(64)
        }
    }

    // ---- softmax (exact; quad shuffles) ----
    float minv[4];
#pragma unroll
    for (int r = 0; r < 4; ++r) {
        float m = -1e30f;
#pragma unroll
        for (int j = 0; j < 12; ++j) m = fmaxf(m, S[j][r]);
        m = fmaxf(m, __shfl_xor(m, 1));
        m = fmaxf(m, __shfl_xor(m, 2));
        m = fmaxf(m, __shfl_xor(m, 4));
        m = fmaxf(m, __shfl_xor(m, 8));
        float l = 0.f;
#pragma unroll
        for (int j = 0; j < 12; ++j) {
            float p = __expf(S[j][r] - m);
            S[j][r] = p;
            l += p;
        }
        l += __shfl_xor(l, 1);
        l += __shfl_xor(l, 2);
        l += __shfl_xor(l, 4);
        l += __shfl_xor(l, 8);
        minv[r] = 1.0f / l;
    }

    __syncthreads();   // all waves done reading K before P overwrites it

    // ---- write P into packed-XOR A layout [wave][16][192] over the K region ----
    _Float16* Ps = KPs + wid * (16 * 192);
#pragma unroll
    for (int j = 0; j < 12; ++j)
#pragma unroll
        for (int r = 0; r < 4; ++r) {
            int row = quad * 4 + r;
            int col = j * 16 + l16;
            int ch  = (col >> 3) ^ (row & 7);
            Ps[row * 192 + ch * 8 + (col & 7)] = (_Float16)(S[j][r] * minv[r]);
        }

    // ---- O = P V : M=16, K=192 (6 steps), N=64 (4 tiles) ----
    half8 af[6];
#pragma unroll
    for (int k = 0; k < 6; ++k) {
        int ch = (k * 4 + quad) ^ (l16 & 7);
        af[k] = *(const half8*)(&Ps[l16 * 192 + ch * 8]);
    }
    // O tile [16x64] staged into this wave's own P region (wave-local, no
    // barrier; compiler orders LDS read-after-write), then coalesced half8
    // copy-out (128B row segments) instead of 16 scalar 2B stores.
#pragma unroll
    for (int nn = 0; nn < 4; ++nn) {
        floatx4 accO = {};
#pragma unroll
        for (int k = 0; k < 6; ++k) {
            int row = nn * 16 + l16;
            int c   = k * 4 + quad;
            int cs  = (c & ~7) | ((c & 7) ^ (row & 7));
            half8 bv = *(const half8*)(&Vt[row * 192 + cs * 8]);
            accO = MFMA16(af[k], bv, accO);
        }
#pragma unroll
        for (int r = 0; r < 4; ++r) {
            int lrow = quad * 4 + r;
            int lcol = nn * 16 + l16;
            int sc   = (lcol >> 3) ^ (lrow & 7);
            Ps[lrow * 64 + sc * 8 + (lcol & 7)] = (_Float16)accO[r];
        }
    }
#pragma unroll
    for (int i = 0; i < 2; ++i) {
        int g    = lane + 64 * i;
        int lrow = g >> 3, lc = g & 7;
        int sc   = lc ^ (lrow & 7);
        half8 ov = *(const half8*)(&Ps[lrow * 64 + sc * 8]);
        *(half8*)(&attnb[(abase + q0 + wid * 16 + lrow) * 256 + h * 64 + lc * 8]) = ov;
    }
}

// ---------- launch ----------
extern "C" void kernel_launch(void* const* d_in, const int* in_sizes, int n_in,
                              void* d_out, int out_size, void* d_ws, size_t ws_size,
                              hipStream_t stream)
{
    const float* feat = (const float*)d_in[0];
    const float* pos  = (const float*)d_in[1];
    const float* Wq   = (const float*)d_in[2];
    const float* bq   = (const float*)d_in[3];
    const float* Wk   = (const float*)d_in[4];
    const float* bk   = (const float*)d_in[5];
    const float* Wv   = (const float*)d_in[6];
    const float* bv   = (const float*)d_in[7];
    const float* Wo   = (const float*)d_in[8];
    const float* bo   = (const float*)d_in[9];
    const int*   md   = (const int*)d_in[10];
    const int*   tw   = (const int*)d_in[11];
    float*       out  = (float*)d_out;

    _Float16* ws    = (_Float16*)d_ws;
    _Float16* Qb    = ws;
    _Float16* Kb    = Qb + NFEAT;
    _Float16* Vb    = Kb + NFEAT;
    _Float16* attnH = Vb + NFEAT;      // 64 MB of d_ws

    qkv_fused<<<512, 256, 0, stream>>>(feat, Wq, Wk, Wv, bq, bk, bv, Qb, Kb, Vb);

    attn_kernel<<<2048, 256, 0, stream>>>(Qb, Kb, Vb, pos, md, tw, attnH);

    out_gemm<<<512, 256, 0, stream>>>(attnH, Wo, bo, out);
}

// Round 10
// 171.250 us; speedup vs baseline: 1.9980x; 1.9980x over previous
//
#include <hip/hip_runtime.h>
#include <hip/hip_bf16.h>
#include <cstdint>
#include <cstddef>

// ---------- types ----------
typedef __attribute__((ext_vector_type(8))) _Float16 half8;
typedef __attribute__((ext_vector_type(4))) float floatx4;

#define MFMA16(a, b, c) __builtin_amdgcn_mfma_f32_16x16x32_f16((a), (b), (c), 0, 0, 0)

// direct global->LDS DMA, 16B per lane, dest = uniform base + lane*16
#define GLOAD_LDS16(g, l)                                                     \
    __builtin_amdgcn_global_load_lds(                                         \
        (const __attribute__((address_space(1))) void*)(g),                   \
        (__attribute__((address_space(3))) void*)(l), 16, 0, 0)

// Barrier that waits LDS ops only — does NOT drain vmcnt, so register
// prefetch loads issued before it stay in flight across the barrier.
#define BARLG() asm volatile("s_waitcnt lgkmcnt(0)\ns_barrier" ::: "memory")

// Problem constants: A=64, T=512, D=256, H=4, HD=64
#define NFEAT 8388608   // 64*512*256

// ---------- staging helpers ----------
// fp32 source, cvt in-register: 128 rows x 64 cols -> LDS rows of dst_stride,
// XOR swizzle within the 8-chunk slab
__device__ __forceinline__ void stage_f32_s(
    const float* __restrict__ src, _Float16* __restrict__ lds, int tid,
    int dst_stride)
{
#pragma unroll
    for (int i = 0; i < 4; ++i) {
        int g   = tid + 256 * i;           // 1024 groups of 8 halfs
        int row = g >> 3, chd = g & 7;
        int chs = chd ^ (row & 7);
        const float* s = src + (size_t)row * 256 + chs * 8;
        float4 v0 = *(const float4*)s;
        float4 v1 = *(const float4*)(s + 4);
        half8 h = { (_Float16)v0.x, (_Float16)v0.y, (_Float16)v0.z, (_Float16)v0.w,
                    (_Float16)v1.x, (_Float16)v1.y, (_Float16)v1.z, (_Float16)v1.w };
        *(half8*)(&lds[row * dst_stride + chd * 8]) = h;
    }
}

// ---------- fused QKV GEMM (R6 structure + DEPTH-2 register W prefetch) ----------
// 1D grid 512 blocks: xcd = n&7; per XCD: 32 bm x 2 bn. X tile [128x256]
// staged ONCE (fp32->fp16 inline). Then 3 weight GEMMs; W K-tiles are
// prefetched into ping-pong REGISTER buffers TWO steps ahead (covers HBM-miss
// latency on fill-polluted L2), cvt+written to LDS after the barrier. In-loop
// barriers are lgkmcnt-only (BARLG) so prefetch stays in flight.
// LDS 80 KB -> 2 blk/CU. Buffer parity = ks&1 (compile-time; ks unrolled).
__global__ __launch_bounds__(256) void qkv_fused(
    const float* __restrict__ feat,
    const float* __restrict__ Wq, const float* __restrict__ Wk,
    const float* __restrict__ Wv,
    const float* __restrict__ bq, const float* __restrict__ bk,
    const float* __restrict__ bv,
    _Float16* __restrict__ Qb, _Float16* __restrict__ Kb, _Float16* __restrict__ Vb)
{
    __shared__ _Float16 Xs[128 * 256];   // 64 KB, XOR-swizzled per 64-col slab
    __shared__ _Float16 Ws[128 * 64];    // 16 KB

    const int n   = blockIdx.x;
    const int idx = n >> 3;
    const int bm  = (n & 7) * 32 + (idx >> 1);
    const int bn  = idx & 1;

    const int tid  = threadIdx.x;
    const int lane = tid & 63, wid = tid >> 6;
    const int quad = lane >> 4, l16 = lane & 15;
    const int wm = wid & 1, wn = wid >> 1;

    // stage X tile once: 4 slabs of 64 cols
    const float* Xg = feat + (size_t)bm * 128 * 256;
#pragma unroll
    for (int slab = 0; slab < 4; ++slab)
        stage_f32_s(Xg + slab * 64, Xs + slab * 64, tid, 256);

    // W K-tile ping-pong prefetch registers: 2 x (8 float4/thread)
    float4 wa0[4], wa1[4], wb0[4], wb1[4];
    auto loadw = [&](float4* v0, float4* v1, const float* __restrict__ src) {
#pragma unroll
        for (int i = 0; i < 4; ++i) {
            int g = tid + 256 * i, row = g >> 3, chd = g & 7;
            int chs = chd ^ (row & 7);
            const float* s = src + (size_t)row * 256 + chs * 8;
            v0[i] = *(const float4*)s;
            v1[i] = *(const float4*)(s + 4);
        }
    };
    auto writew = [&](const float4* v0, const float4* v1) {
#pragma unroll
        for (int i = 0; i < 4; ++i) {
            int g = tid + 256 * i, row = g >> 3, chd = g & 7;
            half8 h = { (_Float16)v0[i].x, (_Float16)v0[i].y,
                        (_Float16)v0[i].z, (_Float16)v0[i].w,
                        (_Float16)v1[i].x, (_Float16)v1[i].y,
                        (_Float16)v1[i].z, (_Float16)v1[i].w };
            *(half8*)(&Ws[row * 64 + chd * 8]) = h;
        }
    };

    const size_t boff = (size_t)bn * 128 * 256;
    loadw(wa0, wa1, Wq + boff);        // tile u=0 (z=0, ks=0)
    loadw(wb0, wb1, Wq + boff + 64);   // tile u=1 (z=0, ks=1)
    __syncthreads();                   // X tile ready (single full drain)

#pragma unroll 1
    for (int z = 0; z < 3; ++z) {
        const float* Wz   = (z == 0) ? Wq : (z == 1) ? Wk : Wv;
        const float* Wnz  = (z == 0) ? Wk : Wv;   // next z's W (unused at z==2)
        const float* bias = (z == 0) ? bq : (z == 1) ? bk : bv;
        _Float16*    outp = (z == 0) ? Qb : (z == 1) ? Kb : Vb;

        floatx4 acc[4][4] = {};
#pragma unroll
        for (int ks = 0; ks < 4; ++ks) {   // k0 = ks*64, tile u = z*4+ks
            BARLG();                       // prev step's Ws reads complete
            if (ks & 1) writew(wb0, wb1);  // cvt + LDS-write tile u
            else        writew(wa0, wa1);
            // prefetch tile u+2 into the just-consumed buffer
            if (ks == 0) {
                loadw(wa0, wa1, Wz + boff + 128);
            } else if (ks == 1) {
                loadw(wb0, wb1, Wz + boff + 192);
            } else if (ks == 2) {
                if (z < 2) loadw(wa0, wa1, Wnz + boff);
            } else {
                if (z < 2) loadw(wb0, wb1, Wnz + boff + 64);
            }
            BARLG();                       // Ws ready; prefetch stays in flight
#pragma unroll
            for (int kh = 0; kh < 2; ++kh) {
                half8 af[4], bf[4];
#pragma unroll
                for (int mi = 0; mi < 4; ++mi) {
                    int row = wm * 64 + mi * 16 + l16;
                    int cs  = (kh * 4 + quad) ^ (row & 7);
                    af[mi] = *(const half8*)(&Xs[row * 256 + ks * 64 + cs * 8]);
                }
#pragma unroll
                for (int ni = 0; ni < 4; ++ni) {
                    int row = wn * 64 + ni * 16 + l16;
                    int cs  = (kh * 4 + quad) ^ (row & 7);
                    bf[ni] = *(const half8*)(&Ws[row * 64 + cs * 8]);
                }
#pragma unroll
                for (int mi = 0; mi < 4; ++mi)
#pragma unroll
                    for (int ni = 0; ni < 4; ++ni)
                        acc[mi][ni] = MFMA16(af[mi], bf[ni], acc[mi][ni]);
            }
        }

        // epilogue z: C/D layout col = lane&15, row = quad*4 + r
#pragma unroll
        for (int ni = 0; ni < 4; ++ni) {
            int col = bn * 128 + wn * 64 + ni * 16 + l16;
            float bv2 = bias[col];
#pragma unroll
            for (int mi = 0; mi < 4; ++mi)
#pragma unroll
                for (int r = 0; r < 4; ++r) {
                    int row = bm * 128 + wm * 64 + mi * 16 + quad * 4 + r;
                    outp[(size_t)row * 256 + col] = (_Float16)(acc[mi][ni][r] + bv2);
                }
        }
    }
}

// ---------- out GEMM: C[128x128] = attnH[128x256] * Wo^T + bias ----------
// Whole A tile [128x256] staged once via DMA (one drain); Wo K-tiles
// prefetched depth-2 into ping-pong register buffers. LDS 80 KB -> 2 blk/CU.
__global__ __launch_bounds__(256) void out_gemm(
    const _Float16* __restrict__ attnH, const float* __restrict__ Wo,
    const float* __restrict__ bo, float* __restrict__ out)
{
    __shared__ _Float16 As[128 * 256];   // 64 KB: 4 packed slabs [128][64]
    __shared__ _Float16 Bs[128 * 64];    // 16 KB

    const int n   = blockIdx.x;
    const int idx = n >> 3;
    const int bm  = (n & 7) * 32 + (idx >> 1);
    const int bn  = idx & 1;

    const int tid  = threadIdx.x;
    const int lane = tid & 63, wid = tid >> 6;
    const int quad = lane >> 4, l16 = lane & 15;
    const int wm = wid & 1, wn = wid >> 1;

    // ---- stage whole A tile via DMA: 4 slabs x 4 groups/wave ----
#pragma unroll
    for (int slab = 0; slab < 4; ++slab)
#pragma unroll
        for (int i = 0; i < 4; ++i) {
            int grp = wid * 4 + i;             // 16 groups of 8 rows
            int row = grp * 8 + (lane >> 3);
            int sc  = (lane & 7) ^ (row & 7);
            GLOAD_LDS16(attnH + (size_t)(bm * 128 + row) * 256 + slab * 64 + sc * 8,
                        As + slab * 8192 + grp * 512);
        }

    float4 wa0[4], wa1[4], wb0[4], wb1[4];
    auto loadw = [&](float4* v0, float4* v1, const float* __restrict__ src) {
#pragma unroll
        for (int i = 0; i < 4; ++i) {
            int g = tid + 256 * i, row = g >> 3, chd = g & 7;
            int chs = chd ^ (row & 7);
            const float* s = src + (size_t)row * 256 + chs * 8;
            v0[i] = *(const float4*)s;
            v1[i] = *(const float4*)(s + 4);
        }
    };
    auto writew = [&](const float4* v0, const float4* v1) {
#pragma unroll
        for (int i = 0; i < 4; ++i) {
            int g = tid + 256 * i, row = g >> 3, chd = g & 7;
            half8 h = { (_Float16)v0[i].x, (_Float16)v0[i].y,
                        (_Float16)v0[i].z, (_Float16)v0[i].w,
                        (_Float16)v1[i].x, (_Float16)v1[i].y,
                        (_Float16)v1[i].z, (_Float16)v1[i].w };
            *(half8*)(&Bs[row * 64 + chd * 8]) = h;
        }
    };

    const size_t boff = (size_t)bn * 128 * 256;
    loadw(wa0, wa1, Wo + boff);        // tile 0
    loadw(wb0, wb1, Wo + boff + 64);   // tile 1
    __syncthreads();                   // A tile ready (single full drain)

    floatx4 acc[4][4] = {};
#pragma unroll
    for (int ks = 0; ks < 4; ++ks) {
        BARLG();
        if (ks & 1) writew(wb0, wb1);
        else        writew(wa0, wa1);
        if (ks == 0)      loadw(wa0, wa1, Wo + boff + 128);
        else if (ks == 1) loadw(wb0, wb1, Wo + boff + 192);
        BARLG();
#pragma unroll
        for (int kh = 0; kh < 2; ++kh) {
            half8 af[4], bf[4];
#pragma unroll
            for (int mi = 0; mi < 4; ++mi) {
                int row = wm * 64 + mi * 16 + l16;
                int cs  = (kh * 4 + quad) ^ (row & 7);
                af[mi] = *(const half8*)(&As[ks * 8192 + row * 64 + cs * 8]);
            }
#pragma unroll
            for (int ni = 0; ni < 4; ++ni) {
                int row = wn * 64 + ni * 16 + l16;
                int cs  = (kh * 4 + quad) ^ (row & 7);
                bf[ni] = *(const half8*)(&Bs[row * 64 + cs * 8]);
            }
#pragma unroll
            for (int mi = 0; mi < 4; ++mi)
#pragma unroll
                for (int ni = 0; ni < 4; ++ni)
                    acc[mi][ni] = MFMA16(af[mi], bf[ni], acc[mi][ni]);
        }
    }

#pragma unroll
    for (int ni = 0; ni < 4; ++ni) {
        int col = bn * 128 + wn * 64 + ni * 16 + l16;
        float bv = bo[col];
#pragma unroll
        for (int mi = 0; mi < 4; ++mi)
#pragma unroll
            for (int r = 0; r < 4; ++r) {
                int row = bm * 128 + wm * 64 + mi * 16 + quad * 4 + r;
                out[(size_t)row * 256 + col] = acc[mi][ni][r] + bv;
            }
    }
}

// ---------- banded sparse attention (exact R0 form) ----------
// 1D grid 2048: xcd = n&7; per XCD 8 animals x (8 qt x 4 h), h fastest then qt
// (adjacent qtiles share K/V band rows -> same-XCD L2 locality).
__global__ __launch_bounds__(256) void attn_kernel(
    const _Float16* __restrict__ Qb, const _Float16* __restrict__ Kb,
    const _Float16* __restrict__ Vb, const float* __restrict__ positions,
    const int* __restrict__ mdp, const int* __restrict__ twp,
    _Float16* __restrict__ attnb)
{
    const int n   = blockIdx.x;
    const int idx = n >> 3;
    const int a   = (n & 7) * 8 + (idx >> 5);
    const int rem = idx & 31;
    const int qt  = rem >> 2, h = rem & 3;

    const int q0 = qt * 64;
    const int s_base = q0 - 64;
    const int tid = threadIdx.x, lane = tid & 63, wid = tid >> 6;
    const int quad = lane >> 4, l16 = lane & 15;

    // LDS 48 KB -> 3 blocks/CU
    __shared__ _Float16 KPs[192 * 64];   // packed K (XOR), reused as packed P
    __shared__ _Float16 Vt[64 * 192];    // packed V^T (XOR chunk swizzle)

    const size_t abase = (size_t)a * 512;
    const int md = *mdp, tw = *twp;
    const float md2 = (float)(md * md);

    // ---- hoisted per-wave Q fragment + q-position loads ----
    const size_t qrow = abase + q0 + wid * 16 + l16;
    half8 aq0 = *(const half8*)(Qb + qrow * 256 + h * 64 + quad * 8);
    half8 aq1 = *(const half8*)(Qb + qrow * 256 + h * 64 + 32 + quad * 8);
    float qpx[4], qpy[4];
    int trow[4];
#pragma unroll
    for (int r = 0; r < 4; ++r) {
        int m = wid * 16 + quad * 4 + r;
        trow[r] = q0 + m;
        float2 qp = *(const float2*)(positions + (abase + q0 + m) * 2);
        qpx[r] = qp.x;
        qpy[r] = qp.y;
    }

    // ---- stage K band via DMA: packed [192][64], source-side XOR swizzle ----
#pragma unroll
    for (int i = 0; i < 6; ++i) {
        int grp = wid * 6 + i;             // 24 groups of 8 rows
        int si  = grp * 8 + (lane >> 3);
        int sc  = min(max(s_base + si, 0), 511);
        int ch  = (lane & 7) ^ (si & 7);
        GLOAD_LDS16(Kb + (abase + sc) * 256 + h * 64 + ch * 8, KPs + grp * 512);
    }
    // ---- stage V^T packed [64][192], XOR chunk swizzle, paired b32 writes ----
#pragma unroll
    for (int i = 0; i < 3; ++i) {
        int g   = tid + 256 * i;           // 768 pair-groups
        int si2 = (g % 96) * 2;
        int d0  = (g / 96) * 8;
        int sa  = min(max(s_base + si2, 0), 511);
        int sb  = min(max(s_base + si2 + 1, 0), 511);
        half8 v0 = *(const half8*)(Vb + (abase + sa) * 256 + h * 64 + d0);
        half8 v1 = *(const half8*)(Vb + (abase + sb) * 256 + h * 64 + d0);
        int c = si2 >> 3;                  // chunk within 24
#pragma unroll
        for (int j = 0; j < 8; ++j) {
            int d  = d0 + j;
            int cs = (c & ~7) | ((c & 7) ^ (d & 7));
            union { _Float16 hh[2]; uint32_t u; } p;
            p.hh[0] = v0[j]; p.hh[1] = v1[j];
            *(uint32_t*)(&Vt[d * 192 + cs * 8 + (si2 & 7)]) = p.u;
        }
    }
    __syncthreads();

    // ---- S = Q K^T over 12 key tiles ----
    floatx4 S[12];
#pragma unroll
    for (int j = 0; j < 12; ++j) {
        int si = j * 16 + l16;
        half8 bk0 = *(const half8*)(&KPs[si * 64 + ((quad) ^ (si & 7)) * 8]);
        half8 bk1 = *(const half8*)(&KPs[si * 64 + ((4 + quad) ^ (si & 7)) * 8]);
        floatx4 acc = {};
        acc = MFMA16(aq0, bk0, acc);
        acc = MFMA16(aq1, bk1, acc);
        int sr = s_base + si;
        int sc = min(max(sr, 0), 511);
        float2 kp = *(const float2*)(positions + (abase + sc) * 2);
        bool svalid = (sr >= 0) && (sr < 512);
#pragma unroll
        for (int r = 0; r < 4; ++r) {
            float dx = qpx[r] - kp.x, dy = qpy[r] - kp.y;
            float d2 = dx * dx + dy * dy;
            int dt = trow[r] - sr; dt = dt < 0 ? -dt : dt;
            bool ok = svalid && (d2 <= md2) && (dt <= tw);
            S[j][r] = ok ? acc[r] * 0.125f : -1e30f;   // scale = 1/sqrt(64)
        }
    }

    // ---- softmax (exact; quad shuffles) ----
    float minv[4];
#pragma unroll
    for (int r = 0; r < 4; ++r) {
        float m = -1e30f;
#pragma unroll
        for (int j = 0; j < 12; ++j) m = fmaxf(m, S[j][r]);
        m = fmaxf(m, __shfl_xor(m, 1));
        m = fmaxf(m, __shfl_xor(m, 2));
        m = fmaxf(m, __shfl_xor(m, 4));
        m = fmaxf(m, __shfl_xor(m, 8));
        float l = 0.f;
#pragma unroll
        for (int j = 0; j < 12; ++j) {
            float p = __expf(S[j][r] - m);
            S[j][r] = p;
            l += p;
        }
        l += __shfl_xor(l, 1);
        l += __shfl_xor(l, 2);
        l += __shfl_xor(l, 4);
        l += __shfl_xor(l, 8);
        minv[r] = 1.0f / l;
    }

    __syncthreads();   // all waves done reading K before P overwrites it

    // ---- write P into packed-XOR A layout [wave][16][192] over the K region ----
    _Float16* Ps = KPs + wid * (16 * 192);
#pragma unroll
    for (int j = 0; j < 12; ++j)
#pragma unroll
        for (int r = 0; r < 4; ++r) {
            int row = quad * 4 + r;
            int col = j * 16 + l16;
            int ch  = (col >> 3) ^ (row & 7);
            Ps[row * 192 + ch * 8 + (col & 7)] = (_Float16)(S[j][r] * minv[r]);
        }

    // ---- O = P V : M=16, K=192 (6 steps), N=64 (4 tiles) ----
    half8 af[6];
#pragma unroll
    for (int k = 0; k < 6; ++k) {
        int ch = (k * 4 + quad) ^ (l16 & 7);
        af[k] = *(const half8*)(&Ps[l16 * 192 + ch * 8]);
    }
#pragma unroll
    for (int nn = 0; nn < 4; ++nn) {
        floatx4 accO = {};
#pragma unroll
        for (int k = 0; k < 6; ++k) {
            int row = nn * 16 + l16;
            int c   = k * 4 + quad;
            int cs  = (c & ~7) | ((c & 7) ^ (row & 7));
            half8 bv = *(const half8*)(&Vt[row * 192 + cs * 8]);
            accO = MFMA16(af[k], bv, accO);
        }
#pragma unroll
        for (int r = 0; r < 4; ++r) {
            int row = q0 + wid * 16 + quad * 4 + r;
            attnb[(abase + row) * 256 + h * 64 + nn * 16 + l16] = (_Float16)accO[r];
        }
    }
}

// ---------- launch ----------
extern "C" void kernel_launch(void* const* d_in, const int* in_sizes, int n_in,
                              void* d_out, int out_size, void* d_ws, size_t ws_size,
                              hipStream_t stream)
{
    const float* feat = (const float*)d_in[0];
    const float* pos  = (const float*)d_in[1];
    const float* Wq   = (const float*)d_in[2];
    const float* bq   = (const float*)d_in[3];
    const float* Wk   = (const float*)d_in[4];
    const float* bk   = (const float*)d_in[5];
    const float* Wv   = (const float*)d_in[6];
    const float* bv   = (const float*)d_in[7];
    const float* Wo   = (const float*)d_in[8];
    const float* bo   = (const float*)d_in[9];
    const int*   md   = (const int*)d_in[10];
    const int*   tw   = (const int*)d_in[11];
    float*       out  = (float*)d_out;

    _Float16* ws    = (_Float16*)d_ws;
    _Float16* Qb    = ws;
    _Float16* Kb    = Qb + NFEAT;
    _Float16* Vb    = Kb + NFEAT;
    _Float16* attnH = Vb + NFEAT;      // 64 MB of d_ws

    qkv_fused<<<512, 256, 0, stream>>>(feat, Wq, Wk, Wv, bq, bk, bv, Qb, Kb, Vb);

    attn_kernel<<<2048, 256, 0, stream>>>(Qb, Kb, Vb, pos, md, tw, attnH);

    out_gemm<<<512, 256, 0, stream>>>(attnH, Wo, bo, out);
}

// Round 11
// 163.228 us; speedup vs baseline: 2.0962x; 1.0491x over previous
//
#include <hip/hip_runtime.h>
#include <hip/hip_bf16.h>
#include <cstdint>
#include <cstddef>

// ---------- types ----------
typedef __attribute__((ext_vector_type(8))) _Float16 half8;
typedef __attribute__((ext_vector_type(4))) float floatx4;

#define MFMA16(a, b, c) __builtin_amdgcn_mfma_f32_16x16x32_f16((a), (b), (c), 0, 0, 0)

// direct global->LDS DMA, 16B per lane, dest = uniform base + lane*16
#define GLOAD_LDS16(g, l)                                                     \
    __builtin_amdgcn_global_load_lds(                                         \
        (const __attribute__((address_space(1))) void*)(g),                   \
        (__attribute__((address_space(3))) void*)(l), 16, 0, 0)

// Barrier that waits LDS ops only — does NOT drain vmcnt, so register
// prefetch loads issued before it stay in flight across the barrier.
#define BARLG() asm volatile("s_waitcnt lgkmcnt(0)\ns_barrier" ::: "memory")

// Problem constants: A=64, T=512, D=256, H=4, HD=64
#define NFEAT 8388608   // 64*512*256

// ---------- staging helpers ----------
// fp32 source, cvt in-register: 128 rows x 64 cols -> LDS rows of dst_stride,
// XOR swizzle within the 8-chunk slab
__device__ __forceinline__ void stage_f32_s(
    const float* __restrict__ src, _Float16* __restrict__ lds, int tid,
    int dst_stride)
{
#pragma unroll
    for (int i = 0; i < 4; ++i) {
        int g   = tid + 256 * i;           // 1024 groups of 8 halfs
        int row = g >> 3, chd = g & 7;
        int chs = chd ^ (row & 7);
        const float* s = src + (size_t)row * 256 + chs * 8;
        float4 v0 = *(const float4*)s;
        float4 v1 = *(const float4*)(s + 4);
        half8 h = { (_Float16)v0.x, (_Float16)v0.y, (_Float16)v0.z, (_Float16)v0.w,
                    (_Float16)v1.x, (_Float16)v1.y, (_Float16)v1.z, (_Float16)v1.w };
        *(half8*)(&lds[row * dst_stride + chd * 8]) = h;
    }
}

// ---------- fused QKV GEMM (R6 structure: register-prefetched W staging) ----------
// 1D grid 512 blocks: xcd = n&7; per XCD: 32 bm x 2 bn. X tile [128x256]
// staged ONCE (fp32->fp16 inline). Then 3 weight GEMMs; each 64-wide K-step's
// W tile is prefetched into REGISTERS during the previous step's MFMA phase
// and cvt+written to LDS after the barrier. In-loop barriers are
// lgkmcnt-only (BARLG) so prefetch loads stay in flight. LDS 80 KB -> 2 blk/CU.
__global__ __launch_bounds__(256) void qkv_fused(
    const float* __restrict__ feat,
    const float* __restrict__ Wq, const float* __restrict__ Wk,
    const float* __restrict__ Wv,
    const float* __restrict__ bq, const float* __restrict__ bk,
    const float* __restrict__ bv,
    _Float16* __restrict__ Qb, _Float16* __restrict__ Kb, _Float16* __restrict__ Vb)
{
    __shared__ _Float16 Xs[128 * 256];   // 64 KB, XOR-swizzled per 64-col slab
    __shared__ _Float16 Ws[128 * 64];    // 16 KB

    const int n   = blockIdx.x;
    const int idx = n >> 3;
    const int bm  = (n & 7) * 32 + (idx >> 1);
    const int bn  = idx & 1;

    const int tid  = threadIdx.x;
    const int lane = tid & 63, wid = tid >> 6;
    const int quad = lane >> 4, l16 = lane & 15;
    const int wm = wid & 1, wn = wid >> 1;

    // stage X tile once: 4 slabs of 64 cols
    const float* Xg = feat + (size_t)bm * 128 * 256;
#pragma unroll
    for (int slab = 0; slab < 4; ++slab)
        stage_f32_s(Xg + slab * 64, Xs + slab * 64, tid, 256);

    // W K-tile prefetch registers: 128 rows x 64 cols fp32 = 8 float4/thread
    float4 wv0[4], wv1[4];
    auto loadw = [&](const float* __restrict__ src) {
#pragma unroll
        for (int i = 0; i < 4; ++i) {
            int g = tid + 256 * i, row = g >> 3, chd = g & 7;
            int chs = chd ^ (row & 7);
            const float* s = src + (size_t)row * 256 + chs * 8;
            wv0[i] = *(const float4*)s;
            wv1[i] = *(const float4*)(s + 4);
        }
    };
    auto writew = [&]() {
#pragma unroll
        for (int i = 0; i < 4; ++i) {
            int g = tid + 256 * i, row = g >> 3, chd = g & 7;
            half8 h = { (_Float16)wv0[i].x, (_Float16)wv0[i].y,
                        (_Float16)wv0[i].z, (_Float16)wv0[i].w,
                        (_Float16)wv1[i].x, (_Float16)wv1[i].y,
                        (_Float16)wv1[i].z, (_Float16)wv1[i].w };
            *(half8*)(&Ws[row * 64 + chd * 8]) = h;
        }
    };

    const size_t boff = (size_t)bn * 128 * 256;
    loadw(Wq + boff);      // prefetch (z=0, ks=0)
    __syncthreads();       // X tile ready (single full drain per block)

#pragma unroll 1
    for (int z = 0; z < 3; ++z) {
        const float* Wz   = (z == 0) ? Wq : (z == 1) ? Wk : Wv;
        const float* Wnz  = (z == 0) ? Wk : Wv;   // next z's W (unused at z==2)
        const float* bias = (z == 0) ? bq : (z == 1) ? bk : bv;
        _Float16*    outp = (z == 0) ? Qb : (z == 1) ? Kb : Vb;

        floatx4 acc[4][4] = {};
#pragma unroll
        for (int ks = 0; ks < 4; ++ks) {   // k0 = ks*64
            BARLG();                       // prev step's Ws reads complete
            writew();                      // cvt + LDS-write current K-tile
            if (ks < 3)      loadw(Wz + boff + (ks + 1) * 64);   // prefetch next
            else if (z < 2)  loadw(Wnz + boff);
            BARLG();                       // Ws ready; prefetch stays in flight
#pragma unroll
            for (int kh = 0; kh < 2; ++kh) {
                half8 af[4], bf[4];
#pragma unroll
                for (int mi = 0; mi < 4; ++mi) {
                    int row = wm * 64 + mi * 16 + l16;
                    int cs  = (kh * 4 + quad) ^ (row & 7);
                    af[mi] = *(const half8*)(&Xs[row * 256 + ks * 64 + cs * 8]);
                }
#pragma unroll
                for (int ni = 0; ni < 4; ++ni) {
                    int row = wn * 64 + ni * 16 + l16;
                    int cs  = (kh * 4 + quad) ^ (row & 7);
                    bf[ni] = *(const half8*)(&Ws[row * 64 + cs * 8]);
                }
#pragma unroll
                for (int mi = 0; mi < 4; ++mi)
#pragma unroll
                    for (int ni = 0; ni < 4; ++ni)
                        acc[mi][ni] = MFMA16(af[mi], bf[ni], acc[mi][ni]);
            }
        }

        // epilogue z: C/D layout col = lane&15, row = quad*4 + r
#pragma unroll
        for (int ni = 0; ni < 4; ++ni) {
            int col = bn * 128 + wn * 64 + ni * 16 + l16;
            float bv2 = bias[col];
#pragma unroll
            for (int mi = 0; mi < 4; ++mi)
#pragma unroll
                for (int r = 0; r < 4; ++r) {
                    int row = bm * 128 + wm * 64 + mi * 16 + quad * 4 + r;
                    outp[(size_t)row * 256 + col] = (_Float16)(acc[mi][ni][r] + bv2);
                }
        }
    }
}

// ---------- out GEMM: C[128x128] = attnH[128x256] * Wo^T + bias ----------
// Whole A tile [128x256] staged once via DMA (one drain); Wo K-tiles
// register-prefetched like qkv. LDS 80 KB -> 2 blocks/CU.
__global__ __launch_bounds__(256) void out_gemm(
    const _Float16* __restrict__ attnH, const float* __restrict__ Wo,
    const float* __restrict__ bo, float* __restrict__ out)
{
    __shared__ _Float16 As[128 * 256];   // 64 KB: 4 packed slabs [128][64]
    __shared__ _Float16 Bs[128 * 64];    // 16 KB

    const int n   = blockIdx.x;
    const int idx = n >> 3;
    const int bm  = (n & 7) * 32 + (idx >> 1);
    const int bn  = idx & 1;

    const int tid  = threadIdx.x;
    const int lane = tid & 63, wid = tid >> 6;
    const int quad = lane >> 4, l16 = lane & 15;
    const int wm = wid & 1, wn = wid >> 1;

    // ---- stage whole A tile via DMA: 4 slabs x 4 groups/wave ----
#pragma unroll
    for (int slab = 0; slab < 4; ++slab)
#pragma unroll
        for (int i = 0; i < 4; ++i) {
            int grp = wid * 4 + i;             // 16 groups of 8 rows
            int row = grp * 8 + (lane >> 3);
            int sc  = (lane & 7) ^ (row & 7);
            GLOAD_LDS16(attnH + (size_t)(bm * 128 + row) * 256 + slab * 64 + sc * 8,
                        As + slab * 8192 + grp * 512);
        }

    float4 wv0[4], wv1[4];
    auto loadw = [&](const float* __restrict__ src) {
#pragma unroll
        for (int i = 0; i < 4; ++i) {
            int g = tid + 256 * i, row = g >> 3, chd = g & 7;
            int chs = chd ^ (row & 7);
            const float* s = src + (size_t)row * 256 + chs * 8;
            wv0[i] = *(const float4*)s;
            wv1[i] = *(const float4*)(s + 4);
        }
    };
    auto writew = [&]() {
#pragma unroll
        for (int i = 0; i < 4; ++i) {
            int g = tid + 256 * i, row = g >> 3, chd = g & 7;
            half8 h = { (_Float16)wv0[i].x, (_Float16)wv0[i].y,
                        (_Float16)wv0[i].z, (_Float16)wv0[i].w,
                        (_Float16)wv1[i].x, (_Float16)wv1[i].y,
                        (_Float16)wv1[i].z, (_Float16)wv1[i].w };
            *(half8*)(&Bs[row * 64 + chd * 8]) = h;
        }
    };

    const size_t boff = (size_t)bn * 128 * 256;
    loadw(Wo + boff);      // prefetch ks=0
    __syncthreads();       // A tile ready (single full drain)

    floatx4 acc[4][4] = {};
#pragma unroll
    for (int ks = 0; ks < 4; ++ks) {
        BARLG();
        writew();
        if (ks < 3) loadw(Wo + boff + (ks + 1) * 64);
        BARLG();
#pragma unroll
        for (int kh = 0; kh < 2; ++kh) {
            half8 af[4], bf[4];
#pragma unroll
            for (int mi = 0; mi < 4; ++mi) {
                int row = wm * 64 + mi * 16 + l16;
                int cs  = (kh * 4 + quad) ^ (row & 7);
                af[mi] = *(const half8*)(&As[ks * 8192 + row * 64 + cs * 8]);
            }
#pragma unroll
            for (int ni = 0; ni < 4; ++ni) {
                int row = wn * 64 + ni * 16 + l16;
                int cs  = (kh * 4 + quad) ^ (row & 7);
                bf[ni] = *(const half8*)(&Bs[row * 64 + cs * 8]);
            }
#pragma unroll
            for (int mi = 0; mi < 4; ++mi)
#pragma unroll
                for (int ni = 0; ni < 4; ++ni)
                    acc[mi][ni] = MFMA16(af[mi], bf[ni], acc[mi][ni]);
        }
    }

#pragma unroll
    for (int ni = 0; ni < 4; ++ni) {
        int col = bn * 128 + wn * 64 + ni * 16 + l16;
        float bv = bo[col];
#pragma unroll
        for (int mi = 0; mi < 4; ++mi)
#pragma unroll
            for (int r = 0; r < 4; ++r) {
                int row = bm * 128 + wm * 64 + mi * 16 + quad * 4 + r;
                out[(size_t)row * 256 + col] = acc[mi][ni][r] + bv;
            }
    }
}

// ---------- banded sparse attention (exact R0 form) ----------
// 1D grid 2048: xcd = n&7; per XCD 8 animals x (8 qt x 4 h), h fastest then qt
// (adjacent qtiles share K/V band rows -> same-XCD L2 locality).
__global__ __launch_bounds__(256) void attn_kernel(
    const _Float16* __restrict__ Qb, const _Float16* __restrict__ Kb,
    const _Float16* __restrict__ Vb, const float* __restrict__ positions,
    const int* __restrict__ mdp, const int* __restrict__ twp,
    _Float16* __restrict__ attnb)
{
    const int n   = blockIdx.x;
    const int idx = n >> 3;
    const int a   = (n & 7) * 8 + (idx >> 5);
    const int rem = idx & 31;
    const int qt  = rem >> 2, h = rem & 3;

    const int q0 = qt * 64;
    const int s_base = q0 - 64;
    const int tid = threadIdx.x, lane = tid & 63, wid = tid >> 6;
    const int quad = lane >> 4, l16 = lane & 15;

    // LDS 48 KB -> 3 blocks/CU
    __shared__ _Float16 KPs[192 * 64];   // packed K (XOR), reused as packed P
    __shared__ _Float16 Vt[64 * 192];    // packed V^T (XOR chunk swizzle)

    const size_t abase = (size_t)a * 512;
    const int md = *mdp, tw = *twp;
    const float md2 = (float)(md * md);

    // ---- hoisted per-wave Q fragment + q-position loads ----
    const size_t qrow = abase + q0 + wid * 16 + l16;
    half8 aq0 = *(const half8*)(Qb + qrow * 256 + h * 64 + quad * 8);
    half8 aq1 = *(const half8*)(Qb + qrow * 256 + h * 64 + 32 + quad * 8);
    float qpx[4], qpy[4];
    int trow[4];
#pragma unroll
    for (int r = 0; r < 4; ++r) {
        int m = wid * 16 + quad * 4 + r;
        trow[r] = q0 + m;
        float2 qp = *(const float2*)(positions + (abase + q0 + m) * 2);
        qpx[r] = qp.x;
        qpy[r] = qp.y;
    }

    // ---- stage K band via DMA: packed [192][64], source-side XOR swizzle ----
#pragma unroll
    for (int i = 0; i < 6; ++i) {
        int grp = wid * 6 + i;             // 24 groups of 8 rows
        int si  = grp * 8 + (lane >> 3);
        int sc  = min(max(s_base + si, 0), 511);
        int ch  = (lane & 7) ^ (si & 7);
        GLOAD_LDS16(Kb + (abase + sc) * 256 + h * 64 + ch * 8, KPs + grp * 512);
    }
    // ---- stage V^T packed [64][192], XOR chunk swizzle, paired b32 writes ----
#pragma unroll
    for (int i = 0; i < 3; ++i) {
        int g   = tid + 256 * i;           // 768 pair-groups
        int si2 = (g % 96) * 2;
        int d0  = (g / 96) * 8;
        int sa  = min(max(s_base + si2, 0), 511);
        int sb  = min(max(s_base + si2 + 1, 0), 511);
        half8 v0 = *(const half8*)(Vb + (abase + sa) * 256 + h * 64 + d0);
        half8 v1 = *(const half8*)(Vb + (abase + sb) * 256 + h * 64 + d0);
        int c = si2 >> 3;                  // chunk within 24
#pragma unroll
        for (int j = 0; j < 8; ++j) {
            int d  = d0 + j;
            int cs = (c & ~7) | ((c & 7) ^ (d & 7));
            union { _Float16 hh[2]; uint32_t u; } p;
            p.hh[0] = v0[j]; p.hh[1] = v1[j];
            *(uint32_t*)(&Vt[d * 192 + cs * 8 + (si2 & 7)]) = p.u;
        }
    }
    __syncthreads();

    // ---- S = Q K^T over 12 key tiles ----
    floatx4 S[12];
#pragma unroll
    for (int j = 0; j < 12; ++j) {
        int si = j * 16 + l16;
        half8 bk0 = *(const half8*)(&KPs[si * 64 + ((quad) ^ (si & 7)) * 8]);
        half8 bk1 = *(const half8*)(&KPs[si * 64 + ((4 + quad) ^ (si & 7)) * 8]);
        floatx4 acc = {};
        acc = MFMA16(aq0, bk0, acc);
        acc = MFMA16(aq1, bk1, acc);
        int sr = s_base + si;
        int sc = min(max(sr, 0), 511);
        float2 kp = *(const float2*)(positions + (abase + sc) * 2);
        bool svalid = (sr >= 0) && (sr < 512);
#pragma unroll
        for (int r = 0; r < 4; ++r) {
            float dx = qpx[r] - kp.x, dy = qpy[r] - kp.y;
            float d2 = dx * dx + dy * dy;
            int dt = trow[r] - sr; dt = dt < 0 ? -dt : dt;
            bool ok = svalid && (d2 <= md2) && (dt <= tw);
            S[j][r] = ok ? acc[r] * 0.125f : -1e30f;   // scale = 1/sqrt(64)
        }
    }

    // ---- softmax (exact; quad shuffles) ----
    float minv[4];
#pragma unroll
    for (int r = 0; r < 4; ++r) {
        float m = -1e30f;
#pragma unroll
        for (int j = 0; j < 12; ++j) m = fmaxf(m, S[j][r]);
        m = fmaxf(m, __shfl_xor(m, 1));
        m = fmaxf(m, __shfl_xor(m, 2));
        m = fmaxf(m, __shfl_xor(m, 4));
        m = fmaxf(m, __shfl_xor(m, 8));
        float l = 0.f;
#pragma unroll
        for (int j = 0; j < 12; ++j) {
            float p = __expf(S[j][r] - m);
            S[j][r] = p;
            l += p;
        }
        l += __shfl_xor(l, 1);
        l += __shfl_xor(l, 2);
        l += __shfl_xor(l, 4);
        l += __shfl_xor(l, 8);
        minv[r] = 1.0f / l;
    }

    __syncthreads();   // all waves done reading K before P overwrites it

    // ---- write P into packed-XOR A layout [wave][16][192] over the K region ----
    _Float16* Ps = KPs + wid * (16 * 192);
#pragma unroll
    for (int j = 0; j < 12; ++j)
#pragma unroll
        for (int r = 0; r < 4; ++r) {
            int row = quad * 4 + r;
            int col = j * 16 + l16;
            int ch  = (col >> 3) ^ (row & 7);
            Ps[row * 192 + ch * 8 + (col & 7)] = (_Float16)(S[j][r] * minv[r]);
        }

    // ---- O = P V : M=16, K=192 (6 steps), N=64 (4 tiles) ----
    half8 af[6];
#pragma unroll
    for (int k = 0; k < 6; ++k) {
        int ch = (k * 4 + quad) ^ (l16 & 7);
        af[k] = *(const half8*)(&Ps[l16 * 192 + ch * 8]);
    }
#pragma unroll
    for (int nn = 0; nn < 4; ++nn) {
        floatx4 accO = {};
#pragma unroll
        for (int k = 0; k < 6; ++k) {
            int row = nn * 16 + l16;
            int c   = k * 4 + quad;
            int cs  = (c & ~7) | ((c & 7) ^ (row & 7));
            half8 bv = *(const half8*)(&Vt[row * 192 + cs * 8]);
            accO = MFMA16(af[k], bv, accO);
        }
#pragma unroll
        for (int r = 0; r < 4; ++r) {
            int row = q0 + wid * 16 + quad * 4 + r;
            attnb[(abase + row) * 256 + h * 64 + nn * 16 + l16] = (_Float16)accO[r];
        }
    }
}

// ---------- launch ----------
extern "C" void kernel_launch(void* const* d_in, const int* in_sizes, int n_in,
                              void* d_out, int out_size, void* d_ws, size_t ws_size,
                              hipStream_t stream)
{
    const float* feat = (const float*)d_in[0];
    const float* pos  = (const float*)d_in[1];
    const float* Wq   = (const float*)d_in[2];
    const float* bq   = (const float*)d_in[3];
    const float* Wk   = (const float*)d_in[4];
    const float* bk   = (const float*)d_in[5];
    const float* Wv   = (const float*)d_in[6];
    const float* bv   = (const float*)d_in[7];
    const float* Wo   = (const float*)d_in[8];
    const float* bo   = (const float*)d_in[9];
    const int*   md   = (const int*)d_in[10];
    const int*   tw   = (const int*)d_in[11];
    float*       out  = (float*)d_out;

    _Float16* ws    = (_Float16*)d_ws;
    _Float16* Qb    = ws;
    _Float16* Kb    = Qb + NFEAT;
    _Float16* Vb    = Kb + NFEAT;
    _Float16* attnH = Vb + NFEAT;      // 64 MB of d_ws

    qkv_fused<<<512, 256, 0, stream>>>(feat, Wq, Wk, Wv, bq, bk, bv, Qb, Kb, Vb);

    attn_kernel<<<2048, 256, 0, stream>>>(Qb, Kb, Vb, pos, md, tw, attnH);

    out_gemm<<<512, 256, 0, stream>>>(attnH, Wo, bo, out);
}